// Round 6
// baseline (326.129 us; speedup 1.0000x reference)
//
#include <hip/hip_runtime.h>

typedef float v4f __attribute__((ext_vector_type(4)));

#define NPTS    1024
#define MGRID   1024
#define NCH     16
#define MAXL    320      // compaction capacity (expected ~170, +12 sigma headroom)
#define UPB     8        // midpoints (u values) per F-table block
#define FSTRIDE 2048     // padded u-stride of the F table
#define CUT     0.32f    // exp(-(x-m)^2/s^2) underflows past |x-m| ~ 0.292

// ---------------------------------------------------------------------------
// Factorization (R5, proven correct): out[b,k,i,j] = B(i-j) * F[b,k](i+j),
//   B(d) = exp(-h^2 d^2 / (4 s^2)),  F[b,k](u) = sum_n exp(-(x_n-m_u)^2/s^2) zc[b,n,k]
// R5 lesson: emit at 2.7 TB/s because each block wrote 18 plane-strided 4KB
// rows (scatter). R6: block = ONE contiguous 64KB chunk of ONE plane (the
// address pattern rocclr fill + R4 fill_linear drain at ~5.7 TB/s), and B/inv
// are recomputed per element (VALU is ~5% busy — recompute is free, the
// store pipe is not).
// ---------------------------------------------------------------------------

// ============================ kernel 1: F table ============================
// grid (256, 4): 8 u's per block, batch in y. ~5-10 us total. (unchanged)
__global__ __launch_bounds__(256)
void f_table_kernel(const float* __restrict__ xz,
                    const float* __restrict__ z,
                    const float* __restrict__ x_grid,
                    const float* __restrict__ log_scale,
                    float* __restrict__ F)
{
    const int ug   = blockIdx.x;        // u-group: u = 8*ug .. 8*ug+7
    const int b    = blockIdx.y;        // batch
    const int tid  = threadIdx.x;
    const int w    = tid >> 6;          // wave 0..3
    const int lane = tid & 63;
    const int u0   = ug * UPB;

    __shared__ float xz_l[MAXL];
    __shared__ v4f   z_l[MAXL * 4];     // 16 floats per point
    __shared__ int   cnts[4];

    const float s2   = __expf(2.0f * log_scale[0]);
    const float ninv = -1.0f / s2;      // exponent coefficient

    // window for this block's midpoint range
    const int  u7  = (u0 + UPB - 1) > 2046 ? 2046 : (u0 + UPB - 1);
    const float m_lo = 0.5f * (x_grid[u0 >> 1] + x_grid[u0 - (u0 >> 1)]);
    const float m_hi = 0.5f * (x_grid[u7 >> 1] + x_grid[u7 - (u7 >> 1)]);
    const float lo = m_lo - CUT, hi = m_hi + CUT;

    // ---- phase 1: predicate + per-wave ballot compaction
    const float* xzb = xz + b * NPTS;
    float xv[4]; unsigned long long msk[4]; int idx[4];
    int base = 0;
    #pragma unroll
    for (int r = 0; r < 4; ++r) {
        const int n = 256 * w + 64 * r + lane;
        xv[r] = xzb[n];
        const bool pred = (xv[r] > lo) && (xv[r] < hi);
        msk[r] = __ballot(pred);
        idx[r] = base + (int)__popcll(msk[r] & ((1ull << lane) - 1ull));
        base += (int)__popcll(msk[r]);
    }
    if (lane == 0) cnts[w] = base;
    __syncthreads();

    int off = 0, total = 0;
    #pragma unroll
    for (int s = 0; s < 4; ++s) { const int c = cnts[s]; if (s < w) off += c; total += c; }
    if (total > MAXL) total = MAXL;

    // ---- phase 2: stage selected points into LDS
    const v4f* zb4 = (const v4f*)(z + (size_t)b * NPTS * NCH);
    #pragma unroll
    for (int r = 0; r < 4; ++r) {
        if ((msk[r] >> lane) & 1ull) {
            const int slot = off + idx[r];
            if (slot < MAXL) {
                const int n = 256 * w + 64 * r + lane;
                xz_l[slot] = xv[r];
                #pragma unroll
                for (int q = 0; q < 4; ++q)
                    z_l[slot * 4 + q] = zb4[n * 4 + q];
            }
        }
    }
    __syncthreads();

    // ---- phase 3: thread (ul, kk) accumulates F[b][kk][u0+ul]
    const int ul = tid >> 5;            // 0..7
    const int kk = tid & 31;            // channel slot; active when < 17 (0 = ones)
    const int u  = u0 + ul;
    const int uu = u > 2046 ? 2046 : u;
    const float xm = 0.5f * (x_grid[uu >> 1] + x_grid[uu - (uu >> 1)]);

    const float* zl = (const float*)z_l;
    const int zidx0 = (kk == 0) ? 0 : (kk - 1);
    const bool isone = (kk == 0);

    float acc = 0.0f;
    for (int t = 0; t < total; ++t) {
        const float d = xz_l[t] - xm;
        const float e = __expf(ninv * (d * d));
        const float val = isone ? 1.0f : zl[t * 16 + zidx0];
        acc += e * val;
    }

    if (kk < 17 && u <= 2046)
        F[((b * 17 + kk) << 11) + u] = acc;   // FSTRIDE = 2048
}

// ============================ kernel 2: emit (chunk-linear) ================
// 4608 blocks; block bid writes f4 [bid*4096, (bid+1)*4096) of big — one
// contiguous 64KB chunk = 16 consecutive rows of plane bid>>6. Pure linear
// write-once stream; per-element table reads (L1/L2-hit) + ~2 transcendentals.
__global__ __launch_bounds__(256)
void emit_linear(const float* __restrict__ x_grid,
                 const float* __restrict__ log_scale,
                 const float* __restrict__ F,
                 float* __restrict__ out)
{
    const int bid = blockIdx.x;        // 0..4607
    const int tid = threadIdx.x;
    const int p   = bid >> 6;          // plane 0..71
    const int ch  = p % 18;            // output channel
    const int b   = p / 18;            // batch
    const int row0 = (bid & 63) * 16;  // 16 rows (i values) per block

    v4f* rp = (v4f*)(out + MGRID) + (size_t)bid * 4096;

    // x_grid passthrough (one block)
    if (bid == 0)
        ((v4f*)out)[tid] = ((const v4f*)x_grid)[tid];

    if (ch == 0) {
        // identity plane chunk
        #pragma unroll
        for (int it = 0; it < 16; ++it) {
            const int Fi  = it * 256 + tid;       // f4 index within chunk
            const int row = row0 + (Fi >> 8);     // i
            const int j0  = (Fi & 255) << 2;      // j of component 0
            v4f v;
            v.x = (j0 + 0 == row) ? 1.f : 0.f;
            v.y = (j0 + 1 == row) ? 1.f : 0.f;
            v.z = (j0 + 2 == row) ? 1.f : 0.f;
            v.w = (j0 + 3 == row) ? 1.f : 0.f;
            rp[Fi] = v;
        }
        return;
    }

    const float s2 = __expf(2.0f * log_scale[0]);
    const float h  = x_grid[1] - x_grid[0];
    const float cB = -(h * h) / (4.0f * s2);
    const float* F0 = F + (b * 17) * FSTRIDE;     // k=0 ("ones") row

    if (ch == 1) {
        // density plane chunk: den = B(i-j) * F0(i+j)
        #pragma unroll
        for (int it = 0; it < 16; ++it) {
            const int Fi  = it * 256 + tid;
            const int row = row0 + (Fi >> 8);
            const int j0  = (Fi & 255) << 2;
            const float fr = (float)(row - j0);
            v4f v;
            #pragma unroll
            for (int l = 0; l < 4; ++l) {
                const float d  = fr - (float)l;
                const float Bv = __expf(cB * d * d);
                v[l] = Bv * F0[row + j0 + l];
            }
            rp[Fi] = v;
        }
        return;
    }

    // ratio plane chunk: val = B*Fk * rcp(B*F0 + eps)
    const float* Fk = F0 + (ch - 1) * FSTRIDE;
    #pragma unroll
    for (int it = 0; it < 16; ++it) {
        const int Fi  = it * 256 + tid;
        const int row = row0 + (Fi >> 8);
        const int j0  = (Fi & 255) << 2;
        const float fr = (float)(row - j0);
        const int u0i = row + j0;
        v4f v;
        #pragma unroll
        for (int l = 0; l < 4; ++l) {
            const float d   = fr - (float)l;
            const float Bv  = __expf(cB * d * d);
            const float den = Bv * F0[u0i + l] + 1e-8f;
            const float num = Bv * Fk[u0i + l];
            v[l] = num * __builtin_amdgcn_rcpf(den);
        }
        rp[Fi] = v;
    }
}

extern "C" void kernel_launch(void* const* d_in, const int* in_sizes, int n_in,
                              void* d_out, int out_size, void* d_ws, size_t ws_size,
                              hipStream_t stream)
{
    const float* xz = (const float*)d_in[0];
    const float* z  = (const float*)d_in[1];
    const float* xg = (const float*)d_in[2];
    const float* ls = (const float*)d_in[3];
    float* out = (float*)d_out;
    float* F   = (float*)d_ws;          // 4*17*2048*4 B = 557 KB

    f_table_kernel<<<dim3(2048 / UPB, 4), dim3(256), 0, stream>>>(xz, z, xg, ls, F);
    emit_linear   <<<dim3(72 * 64),       dim3(256), 0, stream>>>(xg, ls, F, out);
}

// Round 7
// 302.010 us; speedup vs baseline: 1.0799x; 1.0799x over previous
//
#include <hip/hip_runtime.h>

typedef float v4f __attribute__((ext_vector_type(4)));

#define NPTS    1024
#define MGRID   1024
#define NCH     16
#define MAXL    320      // compaction capacity (expected ~170, big headroom)
#define UPB     8        // midpoints (u values) per F-table block
#define FSTRIDE 2048     // padded u-stride of the F table
#define CUT     0.32f    // exp(-(x-m)^2/s^2) underflows past |x-m| ~ 0.292
#define HBAND   96       // band half-width: outside |i-j|>96, |out| < 3e-6

// ---------------------------------------------------------------------------
// R0-R6 ledger: every hand-written store stream we produced drains at
// 1.3-2.7 TB/s (NT/plain, holey/scatter/chunk-linear — all falsified as the
// cause), while rocclr's fillBufferAligned drains the SAME buffer at
// 5.6-6.4 TB/s every iteration. R7: stop fighting it — hipMemsetAsync IS
// that shader (stream-ordered, graph-capturable). Memset the whole output
// to zero at the proven rate, then write only the true information:
//   - F table (R5 factorization, out[b,k,i,j] = B(i-j)*F[b,k](i+j))
//   - the diagonal band |i-j|<=96 of ch1..17  (71 MB — all nonzero bytes;
//     outside the band, ratio <= 4e11*exp(-39.8) ~ 2e-6 << tolerance)
//   - ch0 identity diagonal (4096 floats) + x_grid passthrough
// ---------------------------------------------------------------------------

// ============================ kernel 1: F table ============================
// grid (256, 4): 8 u's per block, batch in y. ~3-5 us. (proven in R5/R6)
__global__ __launch_bounds__(256)
void f_table_kernel(const float* __restrict__ xz,
                    const float* __restrict__ z,
                    const float* __restrict__ x_grid,
                    const float* __restrict__ log_scale,
                    float* __restrict__ F)
{
    const int ug   = blockIdx.x;        // u-group: u = 8*ug .. 8*ug+7
    const int b    = blockIdx.y;        // batch
    const int tid  = threadIdx.x;
    const int w    = tid >> 6;          // wave 0..3
    const int lane = tid & 63;
    const int u0   = ug * UPB;

    __shared__ float xz_l[MAXL];
    __shared__ v4f   z_l[MAXL * 4];     // 16 floats per point
    __shared__ int   cnts[4];

    const float s2   = __expf(2.0f * log_scale[0]);
    const float ninv = -1.0f / s2;      // exponent coefficient

    // window for this block's midpoint range
    const int  u7  = (u0 + UPB - 1) > 2046 ? 2046 : (u0 + UPB - 1);
    const float m_lo = 0.5f * (x_grid[u0 >> 1] + x_grid[u0 - (u0 >> 1)]);
    const float m_hi = 0.5f * (x_grid[u7 >> 1] + x_grid[u7 - (u7 >> 1)]);
    const float lo = m_lo - CUT, hi = m_hi + CUT;

    // ---- phase 1: predicate + per-wave ballot compaction
    const float* xzb = xz + b * NPTS;
    float xv[4]; unsigned long long msk[4]; int idx[4];
    int base = 0;
    #pragma unroll
    for (int r = 0; r < 4; ++r) {
        const int n = 256 * w + 64 * r + lane;
        xv[r] = xzb[n];
        const bool pred = (xv[r] > lo) && (xv[r] < hi);
        msk[r] = __ballot(pred);
        idx[r] = base + (int)__popcll(msk[r] & ((1ull << lane) - 1ull));
        base += (int)__popcll(msk[r]);
    }
    if (lane == 0) cnts[w] = base;
    __syncthreads();

    int off = 0, total = 0;
    #pragma unroll
    for (int s = 0; s < 4; ++s) { const int c = cnts[s]; if (s < w) off += c; total += c; }
    if (total > MAXL) total = MAXL;

    // ---- phase 2: stage selected points into LDS
    const v4f* zb4 = (const v4f*)(z + (size_t)b * NPTS * NCH);
    #pragma unroll
    for (int r = 0; r < 4; ++r) {
        if ((msk[r] >> lane) & 1ull) {
            const int slot = off + idx[r];
            if (slot < MAXL) {
                const int n = 256 * w + 64 * r + lane;
                xz_l[slot] = xv[r];
                #pragma unroll
                for (int q = 0; q < 4; ++q)
                    z_l[slot * 4 + q] = zb4[n * 4 + q];
            }
        }
    }
    __syncthreads();

    // ---- phase 3: thread (ul, kk) accumulates F[b][kk][u0+ul]
    const int ul = tid >> 5;            // 0..7
    const int kk = tid & 31;            // channel slot; active when < 17 (0 = ones)
    const int u  = u0 + ul;
    const int uu = u > 2046 ? 2046 : u;
    const float xm = 0.5f * (x_grid[uu >> 1] + x_grid[uu - (uu >> 1)]);

    const float* zl = (const float*)z_l;
    const int zidx0 = (kk == 0) ? 0 : (kk - 1);
    const bool isone = (kk == 0);

    float acc = 0.0f;
    for (int t = 0; t < total; ++t) {
        const float d = xz_l[t] - xm;
        const float e = __expf(ninv * (d * d));
        const float val = isone ? 1.0f : zl[t * 16 + zidx0];
        acc += e * val;
    }

    if (kk < 17 && u <= 2046)
        F[((b * 17 + kk) << 11) + u] = acc;   // FSTRIDE = 2048
}

// ============================ kernel 2: band emit ==========================
// One wave per (plane, row): writes the 256-float aligned segment covering
// the |i-j|<=96 band (64 f4 stores = 1 KB contiguous per wave). ch0 planes:
// diagonal 1.0 + x_grid passthrough only. Everything else stays memset-zero.
__global__ __launch_bounds__(256)
void band_kernel(const float* __restrict__ x_grid,
                 const float* __restrict__ log_scale,
                 const float* __restrict__ F,
                 float* __restrict__ out)
{
    const int job  = blockIdx.x * 4 + (threadIdx.x >> 6);  // 0..73727
    const int lane = threadIdx.x & 63;
    const int p    = job >> 10;          // plane 0..71  (= b*18 + ch)
    const int i    = job & 1023;         // row
    const int ch   = p % 18;
    const int b    = p / 18;

    float* big = out + MGRID;
    const size_t plane = (size_t)MGRID * MGRID;
    float* rb = big + (size_t)p * plane + (size_t)i * MGRID;

    if (ch == 0) {
        // identity diagonal + x_grid passthrough (rest is memset zero)
        if (lane == 0) rb[i] = 1.0f;
        if (p == 0 && lane == 1) out[i] = x_grid[i];
        return;
    }

    const float s2 = __expf(2.0f * log_scale[0]);
    const float h  = x_grid[1] - x_grid[0];
    const float cB = -(h * h) / (4.0f * s2);

    const float* F0 = F + (b * 17) * FSTRIDE;      // k=0 ("ones") row
    const float* Fk = F0 + (ch - 1) * FSTRIDE;     // this channel's row

    // 256-float aligned segment covering [i-96, i+96]
    int start = (i - HBAND) & ~3;
    if (start < 0) start = 0;
    if (start > MGRID - 256) start = MGRID - 256;
    const int j0 = start + 4 * lane;               // this lane's first j

    v4f v;
    if (ch == 1) {
        // density: B(i-j) * F0(i+j)
        #pragma unroll
        for (int l = 0; l < 4; ++l) {
            const int   j = j0 + l;
            const float d = (float)(i - j);
            const float B = __expf(cB * d * d);
            v[l] = B * F0[i + j];
        }
    } else {
        // ratio: B*Fk / (B*F0 + eps)
        #pragma unroll
        for (int l = 0; l < 4; ++l) {
            const int   j   = j0 + l;
            const float d   = (float)(i - j);
            const float B   = __expf(cB * d * d);
            const float den = B * F0[i + j] + 1e-8f;
            v[l] = (B * Fk[i + j]) * __builtin_amdgcn_rcpf(den);
        }
    }
    *(v4f*)(rb + j0) = v;    // rb 4KB-aligned, j0 multiple of 4 -> 16B aligned
}

extern "C" void kernel_launch(void* const* d_in, const int* in_sizes, int n_in,
                              void* d_out, int out_size, void* d_ws, size_t ws_size,
                              hipStream_t stream)
{
    const float* xz = (const float*)d_in[0];
    const float* z  = (const float*)d_in[1];
    const float* xg = (const float*)d_in[2];
    const float* ls = (const float*)d_in[3];
    float* out = (float*)d_out;
    float* F   = (float*)d_ws;          // 4*17*2048*4 B = 557 KB

    // Bulk zero at the proven rocclr-fill rate (~5.9 TB/s on this buffer).
    hipMemsetAsync(out, 0, (size_t)out_size, stream);

    // F table (557 KB of real info), then the 71 MB diagonal band + diag/grid.
    f_table_kernel<<<dim3(2048 / UPB, 4), dim3(256), 0, stream>>>(xz, z, xg, ls, F);
    band_kernel   <<<dim3(73728 / 4),     dim3(256), 0, stream>>>(xg, ls, F, out);
}

// Round 8
// 294.766 us; speedup vs baseline: 1.1064x; 1.0246x over previous
//
#include <hip/hip_runtime.h>

typedef float v4f __attribute__((ext_vector_type(4)));

#define NPTS    1024
#define MGRID   1024
#define MAXL    320      // compaction capacity (expected ~170, big headroom)
#define UPB     8        // midpoints (u values) per F-table block
#define FSTRIDE 2048     // padded u-stride of the F table
#define CUT     0.32f    // exp(-(x-m)^2/s^2) underflows past |x-m| ~ 0.292
#define HBAND   96       // band half-width: outside |i-j|>96, |out| < 1e-6

// ---------------------------------------------------------------------------
// Session ledger (R0-R7): output = B(i-j)*F[b,k](i+j) factorization (R5).
// Store-rate law (resolved R7): PURE store streams drain at 4.8-6.2 TB/s
// (rocclr fill, R1/R4 fills); any kernel mixing loads+VALU into the store
// stream caps at 1.3-2.7 TB/s (R0/R3/R5/R6) — waves stall on load latency
// between stores and the write queue starves. Structure therefore:
//   1. hipMemsetAsync whole output (302 MB @ rocclr rate)   [pure]
//   2. f_table (557 KB of real information)                 [tiny]
//   3. band kernel: only the |i-j|<=96 diagonal band (72 MB) [mixed, small]
// R8 change: band kernel processes 4 rows per wave — hoist all 32 table
// loads, compute, then 4 back-to-back 1KB stores (4x outstanding stores,
// load latency amortized per 4KB instead of per 1KB).
// ---------------------------------------------------------------------------

// ============================ kernel 1: F table ============================
// grid (256, 4): 8 u's per block, batch in y. ~3-5 us. (proven R5-R7)
__global__ __launch_bounds__(256)
void f_table_kernel(const float* __restrict__ xz,
                    const float* __restrict__ z,
                    const float* __restrict__ x_grid,
                    const float* __restrict__ log_scale,
                    float* __restrict__ F)
{
    const int ug   = blockIdx.x;        // u-group: u = 8*ug .. 8*ug+7
    const int b    = blockIdx.y;        // batch
    const int tid  = threadIdx.x;
    const int w    = tid >> 6;          // wave 0..3
    const int lane = tid & 63;
    const int u0   = ug * UPB;

    __shared__ float xz_l[MAXL];
    __shared__ v4f   z_l[MAXL * 4];     // 16 floats per point
    __shared__ int   cnts[4];

    const float s2   = __expf(2.0f * log_scale[0]);
    const float ninv = -1.0f / s2;      // exponent coefficient

    // window for this block's midpoint range
    const int  u7  = (u0 + UPB - 1) > 2046 ? 2046 : (u0 + UPB - 1);
    const float m_lo = 0.5f * (x_grid[u0 >> 1] + x_grid[u0 - (u0 >> 1)]);
    const float m_hi = 0.5f * (x_grid[u7 >> 1] + x_grid[u7 - (u7 >> 1)]);
    const float lo = m_lo - CUT, hi = m_hi + CUT;

    // ---- phase 1: predicate + per-wave ballot compaction
    const float* xzb = xz + b * NPTS;
    float xv[4]; unsigned long long msk[4]; int idx[4];
    int base = 0;
    #pragma unroll
    for (int r = 0; r < 4; ++r) {
        const int n = 256 * w + 64 * r + lane;
        xv[r] = xzb[n];
        const bool pred = (xv[r] > lo) && (xv[r] < hi);
        msk[r] = __ballot(pred);
        idx[r] = base + (int)__popcll(msk[r] & ((1ull << lane) - 1ull));
        base += (int)__popcll(msk[r]);
    }
    if (lane == 0) cnts[w] = base;
    __syncthreads();

    int off = 0, total = 0;
    #pragma unroll
    for (int s = 0; s < 4; ++s) { const int c = cnts[s]; if (s < w) off += c; total += c; }
    if (total > MAXL) total = MAXL;

    // ---- phase 2: stage selected points into LDS
    const v4f* zb4 = (const v4f*)(z + (size_t)b * NPTS * 16);
    #pragma unroll
    for (int r = 0; r < 4; ++r) {
        if ((msk[r] >> lane) & 1ull) {
            const int slot = off + idx[r];
            if (slot < MAXL) {
                const int n = 256 * w + 64 * r + lane;
                xz_l[slot] = xv[r];
                #pragma unroll
                for (int q = 0; q < 4; ++q)
                    z_l[slot * 4 + q] = zb4[n * 4 + q];
            }
        }
    }
    __syncthreads();

    // ---- phase 3: thread (ul, kk) accumulates F[b][kk][u0+ul]
    const int ul = tid >> 5;            // 0..7
    const int kk = tid & 31;            // channel slot; active when < 17 (0 = ones)
    const int u  = u0 + ul;
    const int uu = u > 2046 ? 2046 : u;
    const float xm = 0.5f * (x_grid[uu >> 1] + x_grid[uu - (uu >> 1)]);

    const float* zl = (const float*)z_l;
    const int zidx0 = (kk == 0) ? 0 : (kk - 1);
    const bool isone = (kk == 0);

    float acc = 0.0f;
    for (int t = 0; t < total; ++t) {
        const float d = xz_l[t] - xm;
        const float e = __expf(ninv * (d * d));
        const float val = isone ? 1.0f : zl[t * 16 + zidx0];
        acc += e * val;
    }

    if (kk < 17 && u <= 2046)
        F[((b * 17 + kk) << 11) + u] = acc;   // FSTRIDE = 2048
}

// ============================ kernel 2: band emit v2 =======================
// Wave-jobs:
//   0..17407     : value band — 68 planes (4 batches x 17 value chans) x 256
//                  row-groups; each wave does 4 consecutive rows: 32 hoisted
//                  loads -> compute -> 4 back-to-back 1KB stores.
//   17408..17471 : ch0 identity diagonal (4 planes x 16 chunks of 64)
//   17472        : x_grid passthrough
__global__ __launch_bounds__(256)
void band2_kernel(const float* __restrict__ x_grid,
                  const float* __restrict__ log_scale,
                  const float* __restrict__ F,
                  float* __restrict__ out)
{
    const int job  = blockIdx.x * 4 + (threadIdx.x >> 6);
    const int lane = threadIdx.x & 63;

    float* big = out + MGRID;
    const size_t plane = (size_t)MGRID * MGRID;

    if (job >= 17408) {
        if (job < 17472) {
            const int t  = job - 17408;   // 0..63
            const int pc = t >> 4;        // batch
            const int c  = t & 15;
            const int i  = c * 64 + lane;
            big[(size_t)(pc * 18) * plane + (size_t)i * MGRID + i] = 1.0f;
        } else if (job == 17472) {
            #pragma unroll
            for (int q = 0; q < 4; ++q) {
                const int f4i = q * 64 + lane;
                ((v4f*)out)[f4i] = ((const v4f*)x_grid)[f4i];
            }
        }
        return;
    }

    const int p  = job >> 8;          // value-plane 0..67
    const int rg = job & 255;         // row group
    const int b  = p / 17;
    const int vc = p % 17;            // 0 = density (out ch1), 1..16 = ratios
    const int i0 = rg * 4;

    const float s2 = __expf(2.0f * log_scale[0]);
    const float h  = x_grid[1] - x_grid[0];
    const float cB = -(h * h) / (4.0f * s2);

    const float* F0 = F + (b * 17) * FSTRIDE;
    const float* Fk = F0 + vc * FSTRIDE;          // vc=0 -> F0 (density path)
    float* pb = big + (size_t)(b * 18 + 1 + vc) * plane;

    // ---- hoisted loads for 4 rows
    int   st[4];
    float f0v[4][4], fkv[4][4];
    #pragma unroll
    for (int r = 0; r < 4; ++r) {
        const int i = i0 + r;
        int s = (i - HBAND) & ~3;
        s = s < 0 ? 0 : (s > MGRID - 256 ? MGRID - 256 : s);
        st[r] = s;
        const int u = i + s + 4 * lane;           // max 2046 at i=1023 ✓
        #pragma unroll
        for (int l = 0; l < 4; ++l) {
            f0v[r][l] = F0[u + l];
            fkv[r][l] = Fk[u + l];
        }
    }

    // ---- compute 4 rows
    v4f vals[4];
    #pragma unroll
    for (int r = 0; r < 4; ++r) {
        const int i  = i0 + r;
        const int j0 = st[r] + 4 * lane;
        #pragma unroll
        for (int l = 0; l < 4; ++l) {
            const float d = (float)(i - (j0 + l));
            const float B = __expf(cB * d * d);
            if (vc == 0) {
                vals[r][l] = B * f0v[r][l];                       // density
            } else {
                const float den = B * f0v[r][l] + 1e-8f;
                vals[r][l] = (B * fkv[r][l]) * __builtin_amdgcn_rcpf(den);
            }
        }
    }

    // ---- 4 back-to-back 1KB stores
    #pragma unroll
    for (int r = 0; r < 4; ++r)
        *(v4f*)(pb + (size_t)(i0 + r) * MGRID + st[r] + 4 * lane) = vals[r];
}

extern "C" void kernel_launch(void* const* d_in, const int* in_sizes, int n_in,
                              void* d_out, int out_size, void* d_ws, size_t ws_size,
                              hipStream_t stream)
{
    const float* xz = (const float*)d_in[0];
    const float* z  = (const float*)d_in[1];
    const float* xg = (const float*)d_in[2];
    const float* ls = (const float*)d_in[3];
    float* out = (float*)d_out;
    float* F   = (float*)d_ws;          // 4*17*2048*4 B = 557 KB

    // Bulk zero at the proven rocclr-fill rate (pure store stream).
    hipMemsetAsync(out, 0, (size_t)out_size, stream);

    // F table (557 KB of real info), then the 72 MB band + diag + x_grid.
    f_table_kernel<<<dim3(2048 / UPB, 4), dim3(256), 0, stream>>>(xz, z, xg, ls, F);
    band2_kernel  <<<dim3((17473 + 3) / 4), dim3(256), 0, stream>>>(xg, ls, F, out);
}